// Round 2
// baseline (3742.386 us; speedup 1.0000x reference)
//
#include <hip/hip_runtime.h>
#include <stdint.h>

// Problem constants
#define G 8
#define H 512
#define I_RAW 1028
#define I_PAD 1056          // padded K for the input GEMM (multiple of 32)
#define BB 128              // batch
#define TT 64               // seq len
#define GH (G*H)            // 4096
#define G3H (G*3*H)         // 12288
#define M_TOT (BB*TT)       // 8192
#define N3H (3*H)           // 1536

typedef __attribute__((ext_vector_type(8))) short bf16x8;
typedef __attribute__((ext_vector_type(4))) float f32x4;

__device__ __forceinline__ unsigned short f2bf(float f) {
  unsigned int u = __float_as_uint(f);
  u += 0x7fffu + ((u >> 16) & 1u);   // round-to-nearest-even
  return (unsigned short)(u >> 16);
}
__device__ __forceinline__ float bf2f(unsigned short h) {
  return __uint_as_float(((unsigned int)h) << 16);
}

// ---------------- pack kernels ----------------
__global__ void k_pack_x(const float* __restrict__ z, const float* __restrict__ a,
                         unsigned short* __restrict__ xb) {
  int idx = blockIdx.x * 256 + threadIdx.x;
  if (idx >= M_TOT * I_PAD) return;
  int m = idx / I_PAD, i = idx % I_PAD;
  int b = m >> 6, t = m & 63;
  float v = 0.f;
  if (i < 4)            v = a[((size_t)b * TT + t) * 4 + i];
  else if (i < I_RAW)   v = z[((size_t)b * TT + t) * 1024 + (i - 4)];
  xb[idx] = f2bf(v);
}

__global__ void k_pack_wih(const float* __restrict__ w, unsigned short* __restrict__ wb) {
  int idx = blockIdx.x * 256 + threadIdx.x;
  if (idx >= G * N3H * I_PAD) return;
  int gj = idx / I_PAD, i = idx % I_PAD;   // gj = g*1536 + j
  float v = (i < I_RAW) ? w[(size_t)gj * I_RAW + i] : 0.f;
  wb[idx] = f2bf(v);
}

__global__ void k_pack_whh(const float* __restrict__ w, unsigned short* __restrict__ wb) {
  int idx = blockIdx.x * 256 + threadIdx.x;
  if (idx >= G * N3H * H) return;
  wb[idx] = f2bf(w[idx]);
}

__global__ void k_init_h(const float* __restrict__ h, float* __restrict__ hf0,
                         unsigned short* __restrict__ hb0) {
  int idx = blockIdx.x * 256 + threadIdx.x;
  if (idx >= BB * GH) return;
  float v = h[idx];
  hf0[idx] = v;
  hb0[idx] = f2bf(v);
}

// ---------------- input-projection GEMM (time-chunked) ----------------
// Chunk rows rc in [0, 128*Tc): rc = b*Tc + tl  (tl = t - t0).
// xp[rc][g*1536+j] = sum_i x[b][t0+tl][i] * Wih[g][j][i]
#define LROW 80   // LDS row stride in bytes (64B data + 16B pad)

__launch_bounds__(256, 2)
__global__ void k_xproj(const unsigned short* __restrict__ xb,
                        const unsigned short* __restrict__ wihb,
                        unsigned short* __restrict__ xp,
                        int t0, int tcShift) {
  __shared__ char lA[128 * LROW];
  __shared__ char lB[128 * LROW];
  int blk = blockIdx.x;
  int by = blk / (G3H / 128);       // m-tiles within chunk
  int bx = blk % (G3H / 128);       // 96 n-tiles
  int m0 = by * 128, n0 = bx * 128;
  int tid = threadIdx.x;
  int lane = tid & 63, wave = tid >> 6;
  int wm = (wave >> 1) * 64, wn = (wave & 1) * 64;
  int tcMask = (1 << tcShift) - 1;

  f32x4 acc[4][4] = {};

  for (int kt = 0; kt < I_PAD / 32; ++kt) {
    int k0 = kt * 32;
#pragma unroll
    for (int p = 0; p < 2; ++p) {
      int row = p * 64 + (tid >> 2);
      int c = (tid & 3) * 16;  // byte within 64B row
      int rc = m0 + row;                       // chunk row
      int b = rc >> tcShift, tl = rc & tcMask; // batch, chunk-local t
      const char* srcA = (const char*)&xb[(size_t)(b * TT + t0 + tl) * I_PAD + k0] + c;
      *(uint4*)(lA + row * LROW + c) = *(const uint4*)srcA;
      const char* srcB = (const char*)&wihb[(size_t)(n0 + row) * I_PAD + k0] + c;
      *(uint4*)(lB + row * LROW + c) = *(const uint4*)srcB;
    }
    __syncthreads();

    bf16x8 af[4], bf[4];
#pragma unroll
    for (int mt = 0; mt < 4; ++mt) {
      int r = wm + mt * 16 + (lane & 15);
      af[mt] = *(const bf16x8*)(lA + r * LROW + ((lane >> 4) * 16));
    }
#pragma unroll
    for (int nt = 0; nt < 4; ++nt) {
      int r = wn + nt * 16 + (lane & 15);
      bf[nt] = *(const bf16x8*)(lB + r * LROW + ((lane >> 4) * 16));
    }
#pragma unroll
    for (int mt = 0; mt < 4; ++mt)
#pragma unroll
      for (int nt = 0; nt < 4; ++nt)
        acc[mt][nt] = __builtin_amdgcn_mfma_f32_16x16x32_bf16(af[mt], bf[nt], acc[mt][nt], 0, 0, 0);
    __syncthreads();
  }

  // epilogue: D[row][col], col = lane&15, row = (lane>>4)*4 + j  [m89-verified]
#pragma unroll
  for (int mt = 0; mt < 4; ++mt)
#pragma unroll
    for (int nt = 0; nt < 4; ++nt)
#pragma unroll
      for (int j = 0; j < 4; ++j) {
        int m = m0 + wm + mt * 16 + (lane >> 4) * 4 + j;   // chunk row
        int n = n0 + wn + nt * 16 + (lane & 15);
        xp[(size_t)m * G3H + n] = f2bf(acc[mt][nt][j]);
      }
}

// ---------------- recurrent step ----------------
// grid: 256 wgs = g(8) x 32 i-tiles of 16 cols. block 256 thr (4 waves).
__global__ void k_step(const unsigned short* __restrict__ xp,  // chunk buffer
                       const unsigned short* __restrict__ whhb,
                       const float* __restrict__ b_ih,
                       const float* __restrict__ b_hh,
                       const float* __restrict__ hf_in,
                       const unsigned short* __restrict__ hb_in,
                       float* __restrict__ hf_out,
                       unsigned short* __restrict__ hb_out,
                       float* __restrict__ out,
                       int t, int tl, int tcShift) {
  __shared__ char hs[64 * 1024];   // 64 rows x 512 bf16, XOR-swizzled
  int blk = blockIdx.x;
  int g = blk >> 5;
  int i0 = (blk & 31) << 4;
  int tid = threadIdx.x, lane = tid & 63, wave = tid >> 6;
  const unsigned short* wg_w = whhb + (size_t)g * N3H * H;

  int c = lane & 15;
  int i = i0 + c;
  float bir = b_ih[g * N3H + 0 * H + i], biz = b_ih[g * N3H + H + i], bin = b_ih[g * N3H + 2 * H + i];
  float bhr = b_hh[g * N3H + 0 * H + i], bhz = b_hh[g * N3H + H + i], bhn = b_hh[g * N3H + 2 * H + i];

  for (int ph = 0; ph < 2; ++ph) {
    if (ph) __syncthreads();   // phase-0 LDS reads done before overwrite
    for (int it = 0; it < 16; ++it) {
      int row = it * 4 + wave;          // 0..63
      int b = ph * 64 + row;
      int cb = lane * 16;
      const char* src = (const char*)&hb_in[(size_t)b * GH + g * H] + cb;
      int dst = row * 1024 + (cb ^ ((row & 7) << 4));
      *(uint4*)(hs + dst) = *(const uint4*)src;
    }
    __syncthreads();

    f32x4 acc[3] = {};
    int rl = wave * 16 + (lane & 15);   // slab-local row
#pragma unroll
    for (int kt = 0; kt < 16; ++kt) {
      int kb = kt * 64 + ((lane >> 4) * 16);
      bf16x8 af = *(const bf16x8*)(hs + rl * 1024 + (kb ^ ((rl & 7) << 4)));
#pragma unroll
      for (int q = 0; q < 3; ++q) {
        int j = q * H + i0 + (lane & 15);
        bf16x8 bf = *(const bf16x8*)&wg_w[(size_t)j * H + kt * 32 + (lane >> 4) * 8];
        acc[q] = __builtin_amdgcn_mfma_f32_16x16x32_bf16(af, bf, acc[q], 0, 0, 0);
      }
    }

    // fused GRU gates. rows b = ph*64 + wave*16 + (lane>>4)*4 + j ; col i
#pragma unroll
    for (int j = 0; j < 4; ++j) {
      int b = ph * 64 + wave * 16 + (lane >> 4) * 4 + j;
      size_t xrow = ((size_t)((b << tcShift) + tl)) * G3H + (size_t)g * N3H;
      float xr = bf2f(xp[xrow + 0 * H + i]);
      float xz = bf2f(xp[xrow + 1 * H + i]);
      float xn = bf2f(xp[xrow + 2 * H + i]);
      float hr = acc[0][j] + bhr;
      float hz = acc[1][j] + bhz;
      float hn = acc[2][j] + bhn;
      float r = 1.f / (1.f + __expf(-(xr + bir + hr)));
      float u = 1.f / (1.f + __expf(-(xz + biz + hz)));
      float nn = xn + bin + r * hn;
      float th = 1.f - 2.f / (1.f + __expf(2.f * nn));   // tanh
      float hprev = hf_in[(size_t)b * GH + g * H + i];
      float hnew = (1.f - u) * th + u * hprev;
      hf_out[(size_t)b * GH + g * H + i] = hnew;
      hb_out[(size_t)b * GH + g * H + i] = f2bf(hnew);
      out[((size_t)b * TT + t) * GH + (size_t)g * H + i] = hnew;
    }
  }
}

// ---------------- launch ----------------
extern "C" void kernel_launch(void* const* d_in, const int* in_sizes, int n_in,
                              void* d_out, int out_size, void* d_ws, size_t ws_size,
                              hipStream_t stream) {
  const float* z    = (const float*)d_in[0];
  const float* a    = (const float*)d_in[1];
  const float* h0   = (const float*)d_in[2];
  const float* Wih  = (const float*)d_in[3];
  const float* Whh  = (const float*)d_in[4];
  const float* bih  = (const float*)d_in[5];
  const float* bhh  = (const float*)d_in[6];
  float* out = (float*)d_out;

  // workspace layout (bytes), all sizes 256-aligned naturally
  char* ws = (char*)d_ws;
  const size_t XB_OFF  = 0;                                   // 8192*1056*2   = 17.3 MB
  const size_t WIH_OFF = XB_OFF  + (size_t)M_TOT * I_PAD * 2; // 12288*1056*2  = 26.0 MB
  const size_t WHH_OFF = WIH_OFF + (size_t)G * N3H * I_PAD * 2; // 12288*512*2 = 12.6 MB
  const size_t HF_OFF  = WHH_OFF + (size_t)G * N3H * H * 2;   // 2*128*4096*4  =  4.2 MB
  const size_t HB_OFF  = HF_OFF  + 2 * (size_t)BB * GH * 4;   // 2*128*4096*2  =  2.1 MB
  const size_t XP_OFF  = HB_OFF  + 2 * (size_t)BB * GH * 2;   // chunk buffer
  const size_t FIXED   = XP_OFF;

  // adaptive time-chunking: largest power-of-2 Tc<=64 whose xp chunk fits ws
  const size_t XP_ROW = (size_t)BB * G3H * 2;   // bytes per time step = 3.15 MB
  int tcShift = 6;
  while (tcShift > 0 && FIXED + (XP_ROW << tcShift) > ws_size) --tcShift;
  const int Tc = 1 << tcShift;

  unsigned short* xb   = (unsigned short*)(ws + XB_OFF);
  unsigned short* wihb = (unsigned short*)(ws + WIH_OFF);
  unsigned short* whhb = (unsigned short*)(ws + WHH_OFF);
  float*          hf   = (float*)(ws + HF_OFF);
  unsigned short* hb   = (unsigned short*)(ws + HB_OFF);
  unsigned short* xp   = (unsigned short*)(ws + XP_OFF);

  float*          hfbuf[2] = { hf, hf + (size_t)BB * GH };
  unsigned short* hbbuf[2] = { hb, hb + (size_t)BB * GH };

  // pack
  {
    int n = M_TOT * I_PAD;
    k_pack_x<<<(n + 255) / 256, 256, 0, stream>>>(z, a, xb);
  }
  {
    int n = G * N3H * I_PAD;
    k_pack_wih<<<(n + 255) / 256, 256, 0, stream>>>(Wih, wihb);
  }
  {
    int n = G * N3H * H;
    k_pack_whh<<<(n + 255) / 256, 256, 0, stream>>>(Whh, whhb);
  }
  {
    int n = BB * GH;
    k_init_h<<<(n + 255) / 256, 256, 0, stream>>>(h0, hfbuf[0], hbbuf[0]);
  }

  // time-chunked: xproj GEMM for chunk, then its Tc scan steps
  for (int t0 = 0; t0 < TT; t0 += Tc) {
    int mtiles = (BB * Tc) / 128;   // = Tc
    k_xproj<<<mtiles * (G3H / 128), 256, 0, stream>>>(xb, wihb, xp, t0, tcShift);
    for (int tl = 0; tl < Tc; ++tl) {
      int t = t0 + tl;
      int cur = t & 1, nxt = (t + 1) & 1;
      k_step<<<256, 256, 0, stream>>>(xp, whhb, bih, bhh,
                                      hfbuf[cur], hbbuf[cur],
                                      hfbuf[nxt], hbbuf[nxt],
                                      out, t, tl, tcShift);
    }
  }
}

// Round 3
// 1448.797 us; speedup vs baseline: 2.5831x; 2.5831x over previous
//
#include <hip/hip_runtime.h>
#include <stdint.h>

// Problem constants
#define G 8
#define H 512
#define I_RAW 1028
#define I_PAD 1056          // padded K for the input GEMM (multiple of 32)
#define BB 128              // batch
#define TT 64               // seq len
#define GH (G*H)            // 4096
#define G3H (G*3*H)         // 12288
#define M_TOT (BB*TT)       // 8192
#define N3H (3*H)           // 1536

typedef __attribute__((ext_vector_type(8))) short bf16x8;
typedef __attribute__((ext_vector_type(4))) float f32x4;

__device__ __forceinline__ unsigned short f2bf(float f) {
  unsigned int u = __float_as_uint(f);
  u += 0x7fffu + ((u >> 16) & 1u);   // round-to-nearest-even
  return (unsigned short)(u >> 16);
}
__device__ __forceinline__ float bf2f(unsigned short h) {
  return __uint_as_float(((unsigned int)h) << 16);
}

// ---------------- pack kernels ----------------
__global__ void k_pack_x(const float* __restrict__ z, const float* __restrict__ a,
                         unsigned short* __restrict__ xb) {
  int idx = blockIdx.x * 256 + threadIdx.x;
  if (idx >= M_TOT * I_PAD) return;
  int m = idx / I_PAD, i = idx % I_PAD;
  int b = m >> 6, t = m & 63;
  float v = 0.f;
  if (i < 4)            v = a[((size_t)b * TT + t) * 4 + i];
  else if (i < I_RAW)   v = z[((size_t)b * TT + t) * 1024 + (i - 4)];
  xb[idx] = f2bf(v);
}

__global__ void k_pack_wih(const float* __restrict__ w, unsigned short* __restrict__ wb) {
  int idx = blockIdx.x * 256 + threadIdx.x;
  if (idx >= G * N3H * I_PAD) return;
  int gj = idx / I_PAD, i = idx % I_PAD;   // gj = g*1536 + j
  float v = (i < I_RAW) ? w[(size_t)gj * I_RAW + i] : 0.f;
  wb[idx] = f2bf(v);
}

__global__ void k_pack_whh(const float* __restrict__ w, unsigned short* __restrict__ wb) {
  int idx = blockIdx.x * 256 + threadIdx.x;
  if (idx >= G * N3H * H) return;
  wb[idx] = f2bf(w[idx]);
}

__global__ void k_init_h(const float* __restrict__ h, float* __restrict__ hf0,
                         unsigned short* __restrict__ hb0) {
  int idx = blockIdx.x * 256 + threadIdx.x;
  if (idx >= BB * GH) return;
  float v = h[idx];
  hf0[idx] = v;
  hb0[idx] = f2bf(v);
}

// ---------------- input-projection GEMM (time-chunked) ----------------
// Chunk rows rc in [0, 128*Tc): rc = b*Tc + tl  (tl = t - t0).
// xp[rc][g*1536+j] = sum_i x[b][t0+tl][i] * Wih[g][j][i]
#define LROW 80   // LDS row stride in bytes (64B data + 16B pad)

__launch_bounds__(256, 2)
__global__ void k_xproj(const unsigned short* __restrict__ xb,
                        const unsigned short* __restrict__ wihb,
                        unsigned short* __restrict__ xp,
                        int t0, int tcShift) {
  __shared__ char lA[128 * LROW];
  __shared__ char lB[128 * LROW];
  int blk = blockIdx.x;
  int by = blk / (G3H / 128);       // m-tiles within chunk
  int bx = blk % (G3H / 128);       // 96 n-tiles
  int m0 = by * 128, n0 = bx * 128;
  int tid = threadIdx.x;
  int lane = tid & 63, wave = tid >> 6;
  int wm = (wave >> 1) * 64, wn = (wave & 1) * 64;
  int tcMask = (1 << tcShift) - 1;

  f32x4 acc[4][4] = {};

  for (int kt = 0; kt < I_PAD / 32; ++kt) {
    int k0 = kt * 32;
#pragma unroll
    for (int p = 0; p < 2; ++p) {
      int row = p * 64 + (tid >> 2);
      int c = (tid & 3) * 16;  // byte within 64B row
      int rc = m0 + row;                       // chunk row
      int b = rc >> tcShift, tl = rc & tcMask; // batch, chunk-local t
      const char* srcA = (const char*)&xb[(size_t)(b * TT + t0 + tl) * I_PAD + k0] + c;
      *(uint4*)(lA + row * LROW + c) = *(const uint4*)srcA;
      const char* srcB = (const char*)&wihb[(size_t)(n0 + row) * I_PAD + k0] + c;
      *(uint4*)(lB + row * LROW + c) = *(const uint4*)srcB;
    }
    __syncthreads();

    bf16x8 af[4], bf[4];
#pragma unroll
    for (int mt = 0; mt < 4; ++mt) {
      int r = wm + mt * 16 + (lane & 15);
      af[mt] = *(const bf16x8*)(lA + r * LROW + ((lane >> 4) * 16));
    }
#pragma unroll
    for (int nt = 0; nt < 4; ++nt) {
      int r = wn + nt * 16 + (lane & 15);
      bf[nt] = *(const bf16x8*)(lB + r * LROW + ((lane >> 4) * 16));
    }
#pragma unroll
    for (int mt = 0; mt < 4; ++mt)
#pragma unroll
      for (int nt = 0; nt < 4; ++nt)
        acc[mt][nt] = __builtin_amdgcn_mfma_f32_16x16x32_bf16(af[mt], bf[nt], acc[mt][nt], 0, 0, 0);
    __syncthreads();
  }

  // epilogue: D[row][col], col = lane&15, row = (lane>>4)*4 + j  [m89-verified]
#pragma unroll
  for (int mt = 0; mt < 4; ++mt)
#pragma unroll
    for (int nt = 0; nt < 4; ++nt)
#pragma unroll
      for (int j = 0; j < 4; ++j) {
        int m = m0 + wm + mt * 16 + (lane >> 4) * 4 + j;   // chunk row
        int n = n0 + wn + nt * 16 + (lane & 15);
        xp[(size_t)m * G3H + n] = f2bf(acc[mt][nt][j]);
      }
}

// ---------------- recurrent step ----------------
// grid 512 = g(8, fastest -> XCD-pinned: blk%8 == XCD) x 32 i-tiles x 2 batch halves.
// No LDS: A (h rows) and B (W_hh cols) fragments read straight from L2.
// Per-XCD working set: one g's W (1.57 MB) + h slab (128 KB) + xp slice -> L2-resident.
__global__ void k_step(const unsigned short* __restrict__ xp,  // chunk buffer
                       const unsigned short* __restrict__ whhb,
                       const float* __restrict__ b_ih,
                       const float* __restrict__ b_hh,
                       const float* __restrict__ hf_in,
                       const unsigned short* __restrict__ hb_in,
                       float* __restrict__ hf_out,
                       unsigned short* __restrict__ hb_out,
                       float* __restrict__ out,
                       int t, int tl, int tcShift) {
  int blk = blockIdx.x;
  int g = blk & 7;                  // XCD pin: same g -> same XCD (round-robin %8)
  int rest = blk >> 3;
  int i0 = (rest & 31) << 4;        // output column tile
  int b0 = (rest >> 5) << 6;        // batch half: 0 or 64
  int tid = threadIdx.x, lane = tid & 63, wave = tid >> 6;
  const unsigned short* wg_w = whhb + (size_t)g * N3H * H;

  int cc = lane & 15;
  int i = i0 + cc;
  float bir = b_ih[g * N3H + 0 * H + i], biz = b_ih[g * N3H + H + i], bin = b_ih[g * N3H + 2 * H + i];
  float bhr = b_hh[g * N3H + 0 * H + i], bhz = b_hh[g * N3H + H + i], bhn = b_hh[g * N3H + 2 * H + i];

  int rl = b0 + wave * 16 + (lane & 15);   // batch row for A fragment
  int klo = (lane >> 4) * 8;               // k sub-offset within 32-wide K step

  f32x4 acc[3] = {};
#pragma unroll
  for (int kt = 0; kt < 16; ++kt) {
    bf16x8 af = *(const bf16x8*)&hb_in[(size_t)rl * GH + g * H + kt * 32 + klo];
#pragma unroll
    for (int q = 0; q < 3; ++q) {
      int j = q * H + i0 + (lane & 15);
      bf16x8 bf = *(const bf16x8*)&wg_w[(size_t)j * H + kt * 32 + klo];
      acc[q] = __builtin_amdgcn_mfma_f32_16x16x32_bf16(af, bf, acc[q], 0, 0, 0);
    }
  }

  // fused GRU gates. rows b = b0 + wave*16 + (lane>>4)*4 + j ; col i
#pragma unroll
  for (int j = 0; j < 4; ++j) {
    int b = b0 + wave * 16 + (lane >> 4) * 4 + j;
    size_t xrow = ((size_t)((b << tcShift) + tl)) * G3H + (size_t)g * N3H;
    float xr = bf2f(xp[xrow + 0 * H + i]);
    float xz = bf2f(xp[xrow + 1 * H + i]);
    float xn = bf2f(xp[xrow + 2 * H + i]);
    float hr = acc[0][j] + bhr;
    float hz = acc[1][j] + bhz;
    float hn = acc[2][j] + bhn;
    float r = 1.f / (1.f + __expf(-(xr + bir + hr)));
    float u = 1.f / (1.f + __expf(-(xz + biz + hz)));
    float nn = xn + bin + r * hn;
    float th = 1.f - 2.f / (1.f + __expf(2.f * nn));   // tanh
    float hprev = hf_in[(size_t)b * GH + g * H + i];
    float hnew = (1.f - u) * th + u * hprev;
    hf_out[(size_t)b * GH + g * H + i] = hnew;
    hb_out[(size_t)b * GH + g * H + i] = f2bf(hnew);
    out[((size_t)b * TT + t) * GH + (size_t)g * H + i] = hnew;
  }
}

// ---------------- launch ----------------
extern "C" void kernel_launch(void* const* d_in, const int* in_sizes, int n_in,
                              void* d_out, int out_size, void* d_ws, size_t ws_size,
                              hipStream_t stream) {
  const float* z    = (const float*)d_in[0];
  const float* a    = (const float*)d_in[1];
  const float* h0   = (const float*)d_in[2];
  const float* Wih  = (const float*)d_in[3];
  const float* Whh  = (const float*)d_in[4];
  const float* bih  = (const float*)d_in[5];
  const float* bhh  = (const float*)d_in[6];
  float* out = (float*)d_out;

  // workspace layout (bytes)
  char* ws = (char*)d_ws;
  const size_t XB_OFF  = 0;                                   // 8192*1056*2   = 17.3 MB
  const size_t WIH_OFF = XB_OFF  + (size_t)M_TOT * I_PAD * 2; // 12288*1056*2  = 26.0 MB
  const size_t WHH_OFF = WIH_OFF + (size_t)G * N3H * I_PAD * 2; // 12288*512*2 = 12.6 MB
  const size_t HF_OFF  = WHH_OFF + (size_t)G * N3H * H * 2;   // 2*128*4096*4  =  4.2 MB
  const size_t HB_OFF  = HF_OFF  + 2 * (size_t)BB * GH * 4;   // 2*128*4096*2  =  2.1 MB
  const size_t XP_OFF  = HB_OFF  + 2 * (size_t)BB * GH * 2;   // chunk buffer
  const size_t FIXED   = XP_OFF;

  // adaptive time-chunking: largest power-of-2 Tc<=64 whose xp chunk fits ws
  const size_t XP_ROW = (size_t)BB * G3H * 2;   // bytes per time step = 3.15 MB
  int tcShift = 6;
  while (tcShift > 0 && FIXED + (XP_ROW << tcShift) > ws_size) --tcShift;
  const int Tc = 1 << tcShift;

  unsigned short* xb   = (unsigned short*)(ws + XB_OFF);
  unsigned short* wihb = (unsigned short*)(ws + WIH_OFF);
  unsigned short* whhb = (unsigned short*)(ws + WHH_OFF);
  float*          hf   = (float*)(ws + HF_OFF);
  unsigned short* hb   = (unsigned short*)(ws + HB_OFF);
  unsigned short* xp   = (unsigned short*)(ws + XP_OFF);

  float*          hfbuf[2] = { hf, hf + (size_t)BB * GH };
  unsigned short* hbbuf[2] = { hb, hb + (size_t)BB * GH };

  // pack
  {
    int n = M_TOT * I_PAD;
    k_pack_x<<<(n + 255) / 256, 256, 0, stream>>>(z, a, xb);
  }
  {
    int n = G * N3H * I_PAD;
    k_pack_wih<<<(n + 255) / 256, 256, 0, stream>>>(Wih, wihb);
  }
  {
    int n = G * N3H * H;
    k_pack_whh<<<(n + 255) / 256, 256, 0, stream>>>(Whh, whhb);
  }
  {
    int n = BB * GH;
    k_init_h<<<(n + 255) / 256, 256, 0, stream>>>(h0, hfbuf[0], hbbuf[0]);
  }

  // time-chunked: xproj GEMM for chunk, then its Tc scan steps
  for (int t0 = 0; t0 < TT; t0 += Tc) {
    int mtiles = (BB * Tc) / 128;   // = Tc
    k_xproj<<<mtiles * (G3H / 128), 256, 0, stream>>>(xb, wihb, xp, t0, tcShift);
    for (int tl = 0; tl < Tc; ++tl) {
      int t = t0 + tl;
      int cur = t & 1, nxt = (t + 1) & 1;
      k_step<<<512, 256, 0, stream>>>(xp, whhb, bih, bhh,
                                      hfbuf[cur], hbbuf[cur],
                                      hfbuf[nxt], hbbuf[nxt],
                                      out, t, tl, tcShift);
    }
  }
}

// Round 4
// 996.961 us; speedup vs baseline: 3.7538x; 1.4532x over previous
//
#include <hip/hip_runtime.h>
#include <stdint.h>

// Problem constants
#define G 8
#define H 512
#define I_RAW 1028
#define I_PAD 1056          // padded K for the input GEMM (multiple of 32)
#define BB 128              // batch
#define TT 64               // seq len
#define GH (G*H)            // 4096
#define G3H (G*3*H)         // 12288
#define M_TOT (BB*TT)       // 8192
#define N3H (3*H)           // 1536

typedef __attribute__((ext_vector_type(8))) short bf16x8;
typedef __attribute__((ext_vector_type(4))) float f32x4;

__device__ __forceinline__ unsigned short f2bf(float f) {
  unsigned int u = __float_as_uint(f);
  u += 0x7fffu + ((u >> 16) & 1u);   // round-to-nearest-even
  return (unsigned short)(u >> 16);
}
__device__ __forceinline__ float bf2f(unsigned short h) {
  return __uint_as_float(((unsigned int)h) << 16);
}

// ---------------- pack kernels ----------------
__global__ void k_pack_x(const float* __restrict__ z, const float* __restrict__ a,
                         unsigned short* __restrict__ xb) {
  int idx = blockIdx.x * 256 + threadIdx.x;
  if (idx >= M_TOT * I_PAD) return;
  int m = idx / I_PAD, i = idx % I_PAD;
  int b = m >> 6, t = m & 63;
  float v = 0.f;
  if (i < 4)            v = a[((size_t)b * TT + t) * 4 + i];
  else if (i < I_RAW)   v = z[((size_t)b * TT + t) * 1024 + (i - 4)];
  xb[idx] = f2bf(v);
}

__global__ void k_pack_wih(const float* __restrict__ w, unsigned short* __restrict__ wb) {
  int idx = blockIdx.x * 256 + threadIdx.x;
  if (idx >= G * N3H * I_PAD) return;
  int gj = idx / I_PAD, i = idx % I_PAD;   // gj = g*1536 + j
  float v = (i < I_RAW) ? w[(size_t)gj * I_RAW + i] : 0.f;
  wb[idx] = f2bf(v);
}

__global__ void k_pack_whh(const float* __restrict__ w, unsigned short* __restrict__ wb) {
  int idx = blockIdx.x * 256 + threadIdx.x;
  if (idx >= G * N3H * H) return;
  wb[idx] = f2bf(w[idx]);
}

__global__ void k_init_h(const float* __restrict__ h, unsigned short* __restrict__ hb0,
                         int* __restrict__ barcnt) {
  int idx = blockIdx.x * 256 + threadIdx.x;
  if (idx < 8 * 16) barcnt[idx] = 0;           // barrier counters (64B-spaced)
  if (idx >= BB * GH) return;
  hb0[idx] = f2bf(h[idx]);
}

// ---------------- input-projection GEMM (time-chunked) ----------------
#define LROW 80   // LDS row stride in bytes (64B data + 16B pad)

__launch_bounds__(256, 2)
__global__ void k_xproj(const unsigned short* __restrict__ xb,
                        const unsigned short* __restrict__ wihb,
                        unsigned short* __restrict__ xp,
                        int t0, int tcShift) {
  __shared__ char lA[128 * LROW];
  __shared__ char lB[128 * LROW];
  int blk = blockIdx.x;
  int by = blk / (G3H / 128);       // m-tiles within chunk
  int bx = blk % (G3H / 128);       // 96 n-tiles
  int m0 = by * 128, n0 = bx * 128;
  int tid = threadIdx.x;
  int lane = tid & 63, wave = tid >> 6;
  int wm = (wave >> 1) * 64, wn = (wave & 1) * 64;
  int tcMask = (1 << tcShift) - 1;

  f32x4 acc[4][4] = {};

  for (int kt = 0; kt < I_PAD / 32; ++kt) {
    int k0 = kt * 32;
#pragma unroll
    for (int p = 0; p < 2; ++p) {
      int row = p * 64 + (tid >> 2);
      int c = (tid & 3) * 16;  // byte within 64B row
      int rc = m0 + row;                       // chunk row
      int b = rc >> tcShift, tl = rc & tcMask; // batch, chunk-local t
      const char* srcA = (const char*)&xb[(size_t)(b * TT + t0 + tl) * I_PAD + k0] + c;
      *(uint4*)(lA + row * LROW + c) = *(const uint4*)srcA;
      const char* srcB = (const char*)&wihb[(size_t)(n0 + row) * I_PAD + k0] + c;
      *(uint4*)(lB + row * LROW + c) = *(const uint4*)srcB;
    }
    __syncthreads();

    bf16x8 af[4], bf[4];
#pragma unroll
    for (int mt = 0; mt < 4; ++mt) {
      int r = wm + mt * 16 + (lane & 15);
      af[mt] = *(const bf16x8*)(lA + r * LROW + ((lane >> 4) * 16));
    }
#pragma unroll
    for (int nt = 0; nt < 4; ++nt) {
      int r = wn + nt * 16 + (lane & 15);
      bf[nt] = *(const bf16x8*)(lB + r * LROW + ((lane >> 4) * 16));
    }
#pragma unroll
    for (int mt = 0; mt < 4; ++mt)
#pragma unroll
      for (int nt = 0; nt < 4; ++nt)
        acc[mt][nt] = __builtin_amdgcn_mfma_f32_16x16x32_bf16(af[mt], bf[nt], acc[mt][nt], 0, 0, 0);
    __syncthreads();
  }

  // epilogue: D[row][col], col = lane&15, row = (lane>>4)*4 + j  [m89-verified]
#pragma unroll
  for (int mt = 0; mt < 4; ++mt)
#pragma unroll
    for (int nt = 0; nt < 4; ++nt)
#pragma unroll
      for (int j = 0; j < 4; ++j) {
        int m = m0 + wm + mt * 16 + (lane >> 4) * 4 + j;   // chunk row
        int n = n0 + wn + nt * 16 + (lane & 15);
        xp[(size_t)m * G3H + n] = f2bf(acc[mt][nt][j]);
      }
}

// ---------------- persistent recurrent scan (cooperative) ----------------
// grid 256 = g(8, fastest -> XCD-pinned blk%8) x 32 i-tiles of 16 cols.
// 512 threads = 8 waves, wave w owns batch rows w*16..w*16+15.
// W_hh fragments for this wg's 48 cols staged ONCE in LDS; h_prev f32 in regs.
// Per step: h bf16 loads (L2) -> 48 MFMA -> gates -> h store -> per-g barrier.
__launch_bounds__(512, 2)
__global__ void k_scan(const unsigned short* __restrict__ xp,
                       const unsigned short* __restrict__ whhb,
                       const float* __restrict__ b_ih,
                       const float* __restrict__ b_hh,
                       const float* __restrict__ hsrc, int hstride,
                       unsigned short* __restrict__ hbuf0,
                       unsigned short* __restrict__ hbuf1,
                       float* __restrict__ out,
                       int* __restrict__ barcnt,
                       int t0, int Tc, int tcShift) {
  __shared__ char wlds[48 * 1024];   // [q][kt][lane] 16B fragments, linear
  int blk = blockIdx.x;
  int g = blk & 7;
  int i0 = (blk >> 3) << 4;
  int tid = threadIdx.x, lane = tid & 63, wave = tid >> 6;
  const unsigned short* wg_w = whhb + (size_t)g * N3H * H;

  // stage W fragments: slot s = q*1024 + kt*64 + l
  for (int s = tid; s < 3072; s += 512) {
    int q = s >> 10, kt = (s >> 6) & 15, l = s & 63;
    int j = q * H + i0 + (l & 15);
    int k = kt * 32 + (l >> 4) * 8;
    *(bf16x8*)(wlds + (size_t)s * 16) = *(const bf16x8*)&wg_w[(size_t)j * H + k];
  }

  int ic = lane & 15;
  int i = i0 + ic;
  float brc = b_ih[g * N3H + 0 * H + i] + b_hh[g * N3H + 0 * H + i];
  float bzc = b_ih[g * N3H + 1 * H + i] + b_hh[g * N3H + 1 * H + i];
  float bin = b_ih[g * N3H + 2 * H + i];
  float bhn = b_hh[g * N3H + 2 * H + i];

  // h_prev f32 in regs: rows b_j = wave*16 + (lane>>4)*4 + j, col i
  float hprev[4];
#pragma unroll
  for (int j = 0; j < 4; ++j) {
    int b = wave * 16 + (lane >> 4) * 4 + j;
    hprev[j] = hsrc[(size_t)b * hstride + g * H + i];
  }

  int arow = wave * 16 + (lane & 15);   // A-fragment batch row
  int akoff = (lane >> 4) * 8;
  int* cnt = &barcnt[g * 16];

  __syncthreads();   // wlds ready

  for (int tl = 0; tl < Tc; ++tl) {
    int t = t0 + tl;
    const unsigned short* hin = (t & 1) ? hbuf1 : hbuf0;
    unsigned short* hout = (t & 1) ? hbuf0 : hbuf1;

    // A loads (h rows), independent -> issued as a batch
    bf16x8 af[16];
#pragma unroll
    for (int kt = 0; kt < 16; ++kt)
      af[kt] = *(const bf16x8*)&hin[(size_t)arow * GH + g * H + kt * 32 + akoff];

    f32x4 acc[3] = {};
#pragma unroll
    for (int kt = 0; kt < 16; ++kt) {
#pragma unroll
      for (int q = 0; q < 3; ++q) {
        bf16x8 wf = *(const bf16x8*)(wlds + ((size_t)(q * 16 + kt) * 64 + lane) * 16);
        acc[q] = __builtin_amdgcn_mfma_f32_16x16x32_bf16(af[kt], wf, acc[q], 0, 0, 0);
      }
    }

    // fused GRU gates; rows b = wave*16 + (lane>>4)*4 + j, col i
#pragma unroll
    for (int j = 0; j < 4; ++j) {
      int b = wave * 16 + (lane >> 4) * 4 + j;
      size_t xrow = ((size_t)((b << tcShift) + tl)) * G3H + (size_t)g * N3H;
      float xr = bf2f(xp[xrow + 0 * H + i]);
      float xz = bf2f(xp[xrow + 1 * H + i]);
      float xn = bf2f(xp[xrow + 2 * H + i]);
      float r = 1.f / (1.f + __expf(-(xr + acc[0][j] + brc)));
      float u = 1.f / (1.f + __expf(-(xz + acc[1][j] + bzc)));
      float nn = xn + bin + r * (acc[2][j] + bhn);
      float th = 1.f - 2.f / (1.f + __expf(2.f * nn));   // tanh
      float hnew = (1.f - u) * th + u * hprev[j];
      hprev[j] = hnew;
      hout[(size_t)b * GH + g * H + i] = f2bf(hnew);
      out[((size_t)b * TT + t) * GH + g * H + i] = hnew;
    }

    // per-g barrier: all 32 wgs of this g finished step t
    asm volatile("s_waitcnt vmcnt(0)" ::: "memory");
    __syncthreads();
    if (tid == 0) {
      __hip_atomic_fetch_add(cnt, 1, __ATOMIC_RELAXED, __HIP_MEMORY_SCOPE_AGENT);
      if (tl != Tc - 1) {
        int target = 32 * (t + 1);
        while (__hip_atomic_load(cnt, __ATOMIC_ACQUIRE, __HIP_MEMORY_SCOPE_AGENT) < target)
          __builtin_amdgcn_s_sleep(1);
      }
    }
    __syncthreads();
  }
}

// ---------------- launch ----------------
extern "C" void kernel_launch(void* const* d_in, const int* in_sizes, int n_in,
                              void* d_out, int out_size, void* d_ws, size_t ws_size,
                              hipStream_t stream) {
  const float* z    = (const float*)d_in[0];
  const float* a    = (const float*)d_in[1];
  const float* h0   = (const float*)d_in[2];
  const float* Wih  = (const float*)d_in[3];
  const float* Whh  = (const float*)d_in[4];
  const float* bih  = (const float*)d_in[5];
  const float* bhh  = (const float*)d_in[6];
  float* out = (float*)d_out;

  // workspace layout (bytes)
  char* ws = (char*)d_ws;
  const size_t XB_OFF  = 0;                                     // 17.3 MB
  const size_t WIH_OFF = XB_OFF  + (size_t)M_TOT * I_PAD * 2;   // 26.0 MB
  const size_t WHH_OFF = WIH_OFF + (size_t)G * N3H * I_PAD * 2; // 12.6 MB
  const size_t HB_OFF  = WHH_OFF + (size_t)G * N3H * H * 2;     // 2 x 1 MB bf16 h ping-pong
  const size_t BAR_OFF = HB_OFF  + 2 * (size_t)BB * GH * 2;     // 512 B barrier counters
  const size_t XP_OFF  = BAR_OFF + 512;
  const size_t FIXED   = XP_OFF;

  // adaptive time-chunking: largest power-of-2 Tc<=64 whose xp chunk fits ws
  const size_t XP_ROW = (size_t)BB * G3H * 2;   // bytes per time step = 3.15 MB
  int tcShift = 6;
  while (tcShift > 0 && FIXED + (XP_ROW << tcShift) > ws_size) --tcShift;
  const int Tc = 1 << tcShift;

  unsigned short* xb   = (unsigned short*)(ws + XB_OFF);
  unsigned short* wihb = (unsigned short*)(ws + WIH_OFF);
  unsigned short* whhb = (unsigned short*)(ws + WHH_OFF);
  unsigned short* hb   = (unsigned short*)(ws + HB_OFF);
  int*            barcnt = (int*)(ws + BAR_OFF);
  unsigned short* xp   = (unsigned short*)(ws + XP_OFF);

  unsigned short* hbuf0 = hb;
  unsigned short* hbuf1 = hb + (size_t)BB * GH;

  // pack
  {
    int n = M_TOT * I_PAD;
    k_pack_x<<<(n + 255) / 256, 256, 0, stream>>>(z, a, xb);
  }
  {
    int n = G * N3H * I_PAD;
    k_pack_wih<<<(n + 255) / 256, 256, 0, stream>>>(Wih, wihb);
  }
  {
    int n = G * N3H * H;
    k_pack_whh<<<(n + 255) / 256, 256, 0, stream>>>(Whh, whhb);
  }
  {
    int n = BB * GH;
    k_init_h<<<(n + 255) / 256, 256, 0, stream>>>(h0, hbuf0, barcnt);
  }

  // time-chunked: xproj GEMM for chunk, then one persistent scan kernel
  for (int t0 = 0; t0 < TT; t0 += Tc) {
    int mtiles = (BB * Tc) / 128;   // = Tc
    k_xproj<<<mtiles * (G3H / 128), 256, 0, stream>>>(xb, wihb, xp, t0, tcShift);

    const float* hsrc = (t0 == 0) ? h0 : (const float*)(out + (size_t)(t0 - 1) * GH);
    int hstride = (t0 == 0) ? GH : TT * GH;
    int t0v = t0, tcv = Tc, tsv = tcShift;
    void* args[] = { (void*)&xp, (void*)&whhb, (void*)&bih, (void*)&bhh,
                     (void*)&hsrc, (void*)&hstride, (void*)&hbuf0, (void*)&hbuf1,
                     (void*)&out, (void*)&barcnt, (void*)&t0v, (void*)&tcv, (void*)&tsv };
    hipLaunchCooperativeKernel((void*)k_scan, dim3(256), dim3(512), args, 0, stream);
  }
}